// Round 3
// 197.081 us; speedup vs baseline: 1.0014x; 1.0014x over previous
//
#include <hip/hip_runtime.h>

// C51 categorical projection. BS = 524288 rows x 51 atoms, fp32.
//
// Round 8: fix R7's correctness failure (absmax 0.67). Root cause: the
// trailing-emission "serialization" loop
//     for (s) if (seg == s) { dst[0]+=accL; ... }
// has four IDENTICAL bodies guarded by mutually-exclusive conditions; the
// compiler may legally merge them into one unguarded body (valid
// per-thread, catastrophic cross-lane): for nd=0 rows all 4 segments then
// RMW the same LDS address at the same instruction -> 3/4 of the row's
// mass lost -> absmax ~0.67. Fix: asm volatile("" ::: "memory") fences
// between the steps pin the four bodies at four distinct program points,
// restoring wave-lockstep serialization as a guarantee.
//
// Design (R6): segmented rows — 4 lanes per row, 16 rows per wave.
// R5 counters: no pipe >27% busy, OccupancyPercent 24%. Binding constraint
// was LDS-per-row (204 B) capping residency plus a 51-iteration serial
// merge chain per lane. 4 lanes/row cuts LDS/wave to 3264 B (occupancy cap
// -> HW max 32 waves/CU via __launch_bounds__(256,8)) and the chain to 13.
//
// Segmented-merge correctness (wave-lockstep):
//  - In-loop: unclamped sibling segments are 13*0.99=12.87 bins apart ->
//    same-instruction emissions never share a bin; clamped lanes never
//    advance -> never emit in-loop. Unrolled iterations have distinct data
//    deps (accL chain) -> not mergeable by the compiler.
//  - All emissions are "+=" into a zeroed row; same-wave LDS ops execute
//    in program order -> cross-segment boundary bins accumulate correctly.
//  - Trailing emissions CAN collide (nd=0 rows) -> serialized into 4
//    fenced predicated steps, one segment at a time.
//  - Segment 3 has 12 real atoms + phantom a=51 with p=0 (harmless: an
//    advance there emits already-accumulated mass at the correct bin).
//
// History: R1 stage+RMW 71us; R2 ds atomics 298us; R3 direct global reads
// 184us; R4 merge-scatter 77us; R5 single-wave blocks 77us (serialization
// structural); R6 infra fail; R7 segmented rows FAILED 0.67 (branch merge).

#define NUM_ATOMS 51
#define ROWS_PER_WAVE 16
#define WAVES_PER_BLOCK 4
#define ROWS_PER_BLOCK (ROWS_PER_WAVE * WAVES_PER_BLOCK)   // 64
#define TILE_FLOATS (ROWS_PER_BLOCK * NUM_ATOMS)           // 3264 = 13056 B
#define QUARTER_FLOATS (ROWS_PER_WAVE * NUM_ATOMS)         // 816
#define QUARTER_V4 (QUARTER_FLOATS / 4)                    // 204 = 3*64 + 12

__global__ __launch_bounds__(256, 8) void catproj_kernel(
    const float* __restrict__ reward,
    const float* __restrict__ probs,
    const float* __restrict__ not_done,
    float* __restrict__ out)
{
    __shared__ __align__(16) float lds[TILE_FLOATS];

    const int tid  = threadIdx.x;          // 0..255
    const int wave = tid >> 6;             // 0..3
    const int lane = tid & 63;
    const int qrow = lane >> 2;            // 0..15: row within wave's quarter
    const int seg  = lane & 3;             // 0..3: 13-atom segment within row

    const int row   = blockIdx.x * ROWS_PER_BLOCK + wave * ROWS_PER_WAVE + qrow;
    const int gbase = blockIdx.x * TILE_FLOATS + wave * QUARTER_FLOATS;

    float* __restrict__ q = lds + wave * QUARTER_FLOATS;   // this wave's 16 rows

    // ---- Stage this wave's 16 rows: contiguous coalesced float4 ----
    const float4* __restrict__ g4 = (const float4*)(probs + gbase);
    float4* __restrict__ q4 = (float4*)q;
#pragma unroll
    for (int k = 0; k < 3; ++k) q4[k * 64 + lane] = g4[k * 64 + lane];
    if (lane < QUARTER_V4 - 192) q4[192 + lane] = g4[192 + lane];

    const float r  = reward[row];          // 4 lanes/row: HW broadcast
    const float nd = not_done[row];
    __syncthreads();

    // ---- Read own 13-atom segment into registers ----
    float* __restrict__ myrow = q + qrow * NUM_ATOMS;
    const int a0 = seg * 13;
    float p[13];
#pragma unroll
    for (int i = 0; i < 12; ++i) p[i] = myrow[a0 + i];
    p[12] = (seg < 3) ? myrow[a0 + 12] : 0.0f;   // phantom atom 51: p = 0
    __syncthreads();

    // ---- Zero own quarter ----
    const float4 z4 = make_float4(0.f, 0.f, 0.f, 0.f);
#pragma unroll
    for (int k = 0; k < 3; ++k) q4[k * 64 + lane] = z4;
    if (lane < QUARTER_V4 - 192) q4[192 + lane] = z4;
    __syncthreads();

    // ---- Segmented merge-scatter: monotone bins, all emissions "+=" ----
    const float c     = 0.99f * nd;
    const float base2 = fmaf(-25.f, c, fmaf(2.5f, r, 25.f)); // 2.5r+25-25c
    const float b0    = fminf(fmaxf(fmaf(c, (float)a0, base2), 0.f), 50.f);
    float curf = floorf(b0);
    float* dst = myrow + (int)curf;
    float accL = 0.f, accU = 0.f;
#pragma unroll
    for (int i = 0; i < 13; ++i) {
        const int a = a0 + i;
        float b = fmaf(c, (float)a, base2);
        b = fminf(fmaxf(b, 0.f), 50.f);
        const float lf = floorf(b);
        const float pa = p[i];
        const float mu = (b - lf) * pa;    // upper mass (0 when b integral)
        const float ml = pa - mu;          // lower mass
        if (lf != curf) {                  // advances by exactly 1 (slope < 1)
            *dst += accL;                  // RMW: boundary bins accumulate
            ++dst;
            accL = accU;
            accU = 0.f;
            curf = lf;
        }
        accL += ml;
        accU += mu;
    }

    // ---- Trailing emission: serialize the 4 segments of each row.
    // Same-instruction collisions are possible here (nd=0 rows collapse all
    // 4 segments onto one dst). The asm fences are REQUIRED: without them
    // the compiler merges the four identical predicated bodies into one
    // unguarded body (legal per-thread), which un-serializes the RMWs and
    // loses mass (R7 failure, absmax 0.67).
    asm volatile("" ::: "memory");
#pragma unroll
    for (int s = 0; s < 4; ++s) {
        if (seg == s) {
            dst[0] += accL;
            if (curf < 50.f) dst[1] += accU;   // accU == 0 when curf == 50
        }
        asm volatile("" ::: "memory");
    }
    __syncthreads();

    // ---- Writeout own quarter: contiguous coalesced float4 ----
    float4* __restrict__ o4 = (float4*)(out + gbase);
#pragma unroll
    for (int k = 0; k < 3; ++k) o4[k * 64 + lane] = q4[k * 64 + lane];
    if (lane < QUARTER_V4 - 192) o4[192 + lane] = q4[192 + lane];
}

extern "C" void kernel_launch(void* const* d_in, const int* in_sizes, int n_in,
                              void* d_out, int out_size, void* d_ws, size_t ws_size,
                              hipStream_t stream) {
    const float* reward   = (const float*)d_in[0];
    const float* probs    = (const float*)d_in[1];
    const float* not_done = (const float*)d_in[2];
    float* out = (float*)d_out;

    const int bs = in_sizes[0];                  // 524288
    const int grid = bs / ROWS_PER_BLOCK;        // 8192 blocks x 256 threads
    catproj_kernel<<<grid, 256, 0, stream>>>(reward, probs, not_done, out);
}

// Round 4
// 195.864 us; speedup vs baseline: 1.0076x; 1.0062x over previous
//
#include <hip/hip_runtime.h>

// C51 categorical projection. BS = 524288 rows x 51 atoms, fp32.
//
// Round 9: R8 post-mortem — occupancy 24->69% but dur only 77->73us, no
// pipe >28% busy. Waves live ~30k cycles each (128 waves/CU x 175k cyc /
// 22 resident) => latency-chain-bound, not occupancy-bound. Two serial
// costs removed this round, both free:
//
// (a) In-loop scatter RMW -> PLAIN ds_write_b32. Proof: in-loop emissions
//     of seg s cover exactly the contiguous run [floor(b(13s)),
//     floor(b(13(s+1)))-1] (merge advances by exactly 1; run empty when
//     clamped or nd=0). Runs of different segs are disjoint (a run is
//     nonempty only if it ends strictly below the next seg's start). Every
//     boundary-bin overlap pairs an in-loop write with a TRAILING emission,
//     and all trailing come later in program order -> in-loop writes each
//     bin exactly once over the whole wave => plain store into zeroed row.
//     Kills the 13 x ~130cyc ds_read->wait->add->write chain.
// (b) __syncthreads -> zero-cost wave fences. All communication is
//     intra-wave (each wave stages/scatters/reads back only its own
//     16-row quarter); the DS unit processes a wave's LDS ops in program
//     order, so the only hazard is the COMPILER sinking/hoisting LDS ops
//     across phases (legal per-thread, wrong cross-lane — the R7 failure
//     class). wave_barrier + asm memory clobber pins order at zero cost.
//
// Trailing emissions stay fenced-RMW (serialized x4): nd=0 rows collapse
// all 4 segs onto one dst; the asm fences are REQUIRED (R7: compiler
// merges identical predicated bodies -> un-serialized RMW -> mass loss).
//
// History: R1 stage+RMW 71us; R2 ds atomics 298us; R3 direct global reads
// 184us; R4 merge-scatter 77us; R5 single-wave blocks 77us; R6 infra fail;
// R7 segmented rows FAILED 0.67 (branch merge); R8 fenced trailing 73us
// PASS (occupancy 69%, VALUBusy 18.6% -> latency-bound on LDS chains).

#define NUM_ATOMS 51
#define ROWS_PER_WAVE 16
#define WAVES_PER_BLOCK 4
#define ROWS_PER_BLOCK (ROWS_PER_WAVE * WAVES_PER_BLOCK)   // 64
#define TILE_FLOATS (ROWS_PER_BLOCK * NUM_ATOMS)           // 3264 = 13056 B
#define QUARTER_FLOATS (ROWS_PER_WAVE * NUM_ATOMS)         // 816
#define QUARTER_V4 (QUARTER_FLOATS / 4)                    // 204 = 3*64 + 12

// Compile-time phase fence: DS unit executes a wave's LDS ops in program
// order; this only stops the compiler from reordering across phases.
// Zero runtime cost.
#define WAVE_FENCE() do { __builtin_amdgcn_wave_barrier(); \
                          asm volatile("" ::: "memory"); } while (0)

__global__ __launch_bounds__(256, 8) void catproj_kernel(
    const float* __restrict__ reward,
    const float* __restrict__ probs,
    const float* __restrict__ not_done,
    float* __restrict__ out)
{
    __shared__ __align__(16) float lds[TILE_FLOATS];

    const int tid  = threadIdx.x;          // 0..255
    const int wave = tid >> 6;             // 0..3
    const int lane = tid & 63;
    const int qrow = lane >> 2;            // 0..15: row within wave's quarter
    const int seg  = lane & 3;             // 0..3: 13-atom segment within row

    const int row   = blockIdx.x * ROWS_PER_BLOCK + wave * ROWS_PER_WAVE + qrow;
    const int gbase = blockIdx.x * TILE_FLOATS + wave * QUARTER_FLOATS;

    float* __restrict__ q = lds + wave * QUARTER_FLOATS;   // this wave's 16 rows

    // ---- Stage this wave's 16 rows: contiguous coalesced float4 ----
    const float4* __restrict__ g4 = (const float4*)(probs + gbase);
    float4* __restrict__ q4 = (float4*)q;
#pragma unroll
    for (int k = 0; k < 3; ++k) q4[k * 64 + lane] = g4[k * 64 + lane];
    if (lane < QUARTER_V4 - 192) q4[192 + lane] = g4[192 + lane];

    const float r  = reward[row];          // 4 lanes/row: HW broadcast
    const float nd = not_done[row];
    WAVE_FENCE();                          // stage (other lanes) -> my reads

    // ---- Read own 13-atom segment into registers ----
    float* __restrict__ myrow = q + qrow * NUM_ATOMS;
    const int a0 = seg * 13;
    float p[13];
#pragma unroll
    for (int i = 0; i < 12; ++i) p[i] = myrow[a0 + i];
    p[12] = (seg < 3) ? myrow[a0 + 12] : 0.0f;   // phantom atom 51: p = 0
    WAVE_FENCE();                          // all reads -> zero writes

    // ---- Zero own quarter ----
    const float4 z4 = make_float4(0.f, 0.f, 0.f, 0.f);
#pragma unroll
    for (int k = 0; k < 3; ++k) q4[k * 64 + lane] = z4;
    if (lane < QUARTER_V4 - 192) q4[192 + lane] = z4;
    WAVE_FENCE();                          // zero -> scatter

    // ---- Segmented merge-scatter: in-loop bins are written exactly once
    // across the wave (disjoint runs) -> PLAIN stores, no RMW chain.
    const float c     = 0.99f * nd;
    const float base2 = fmaf(-25.f, c, fmaf(2.5f, r, 25.f)); // 2.5r+25-25c
    const float b0    = fminf(fmaxf(fmaf(c, (float)a0, base2), 0.f), 50.f);
    float curf = floorf(b0);
    float* dst = myrow + (int)curf;
    float accL = 0.f, accU = 0.f;
#pragma unroll
    for (int i = 0; i < 13; ++i) {
        const int a = a0 + i;
        float b = fmaf(c, (float)a, base2);
        b = fminf(fmaxf(b, 0.f), 50.f);
        const float lf = floorf(b);
        const float pa = p[i];
        const float mu = (b - lf) * pa;    // upper mass (0 when b integral)
        const float ml = pa - mu;          // lower mass
        if (lf != curf) {                  // advances by exactly 1 (slope < 1)
            *dst = accL;                   // PLAIN store: bin owned uniquely
            ++dst;
            accL = accU;
            accU = 0.f;
            curf = lf;
        }
        accL += ml;
        accU += mu;
    }

    // ---- Trailing emission: serialize the 4 segments of each row.
    // Collisions possible here (nd=0 rows collapse all 4 segments onto one
    // dst; boundary bins shared with in-loop stores of sibling segs). The
    // asm fences are REQUIRED: without them the compiler merges the four
    // identical predicated bodies into one unguarded body (R7, absmax 0.67).
    asm volatile("" ::: "memory");
#pragma unroll
    for (int s = 0; s < 4; ++s) {
        if (seg == s) {
            dst[0] += accL;
            if (curf < 50.f) dst[1] += accU;   // accU == 0 when curf == 50
        }
        asm volatile("" ::: "memory");
    }
    WAVE_FENCE();                          // scatter -> readback

    // ---- Writeout own quarter: contiguous coalesced float4 ----
    float4* __restrict__ o4 = (float4*)(out + gbase);
#pragma unroll
    for (int k = 0; k < 3; ++k) o4[k * 64 + lane] = q4[k * 64 + lane];
    if (lane < QUARTER_V4 - 192) o4[192 + lane] = q4[192 + lane];
}

extern "C" void kernel_launch(void* const* d_in, const int* in_sizes, int n_in,
                              void* d_out, int out_size, void* d_ws, size_t ws_size,
                              hipStream_t stream) {
    const float* reward   = (const float*)d_in[0];
    const float* probs    = (const float*)d_in[1];
    const float* not_done = (const float*)d_in[2];
    float* out = (float*)d_out;

    const int bs = in_sizes[0];                  // 524288
    const int grid = bs / ROWS_PER_BLOCK;        // 8192 blocks x 256 threads
    catproj_kernel<<<grid, 256, 0, stream>>>(reward, probs, not_done, out);
}